// Round 1
// baseline (346.112 us; speedup 1.0000x reference)
//
#include <hip/hip_runtime.h>
#include <hip/hip_bf16.h>
#include <stdint.h>

// Problem constants (FC_Caps): B=32, I=1024, O=64, D_out=32, D_in=16
#define B_  32
#define I_  1024
#define O_  64
#define D_  32
#define N_  16
#define OD_ 2048   // O_*D_

// ---------- bf16 helpers (bit-exact RNE pack, shift unpack) ----------
__device__ __forceinline__ uint32_t f2bf1(float f) {
  uint32_t u = __float_as_uint(f);
  return (u + 0x7fffu + ((u >> 16) & 1u)) >> 16;
}
__device__ __forceinline__ uint32_t pack2(float a, float b) {
  return f2bf1(a) | (f2bf1(b) << 16);
}
__device__ __forceinline__ void unpack8(uint4 r, float u[8]) {
  u[0] = __uint_as_float(r.x << 16);
  u[1] = __uint_as_float(r.x & 0xffff0000u);
  u[2] = __uint_as_float(r.y << 16);
  u[3] = __uint_as_float(r.y & 0xffff0000u);
  u[4] = __uint_as_float(r.z << 16);
  u[5] = __uint_as_float(r.z & 0xffff0000u);
  u[6] = __uint_as_float(r.w << 16);
  u[7] = __uint_as_float(r.w & 0xffff0000u);
}

// ---------- K1: u_hat[b][i][od] = sum_n W[i,od,n] * x[b,i,n]  (bf16 out) ----------
// One block per input capsule i; W[i] tile reused across all 32 batches.
// Thread t owns od = t*8 .. t*8+7 (consecutive -> 16B coalesced stores).
__global__ __launch_bounds__(256) void k_einsum(const float* __restrict__ x,
                                                const float* __restrict__ W,
                                                uint4* __restrict__ uhat) {
  const int i = blockIdx.x;
  const int t = threadIdx.x;
  __shared__ float xs[B_ * N_];
  for (int e = t; e < B_ * N_; e += 256) {
    int bb = e >> 4, n = e & 15;
    xs[e] = x[(size_t)bb * (I_ * N_) + (size_t)i * N_ + n];
  }
  // W[i, od, n] flat = i*32768 + od*16 + n ; this thread's 8 rows are contiguous (512 floats)
  float w[8][16];
  const float* Wi = W + (size_t)i * (OD_ * N_) + (size_t)t * (8 * N_);
  #pragma unroll
  for (int k = 0; k < 8; ++k) {
    #pragma unroll
    for (int q = 0; q < 4; ++q) {
      float4 f = ((const float4*)(Wi + k * 16))[q];
      w[k][q * 4 + 0] = f.x; w[k][q * 4 + 1] = f.y;
      w[k][q * 4 + 2] = f.z; w[k][q * 4 + 3] = f.w;
    }
  }
  __syncthreads();
  for (int bb = 0; bb < B_; ++bb) {
    float xv[16];
    #pragma unroll
    for (int q = 0; q < 4; ++q) {
      float4 f = ((const float4*)(xs + bb * 16))[q];   // LDS broadcast (all lanes same addr)
      xv[q * 4 + 0] = f.x; xv[q * 4 + 1] = f.y;
      xv[q * 4 + 2] = f.z; xv[q * 4 + 3] = f.w;
    }
    float acc[8];
    #pragma unroll
    for (int k = 0; k < 8; ++k) {
      float a = 0.f;
      #pragma unroll
      for (int n = 0; n < 16; ++n) a = fmaf(w[k][n], xv[n], a);
      acc[k] = a;
    }
    uint4 outv = make_uint4(pack2(acc[0], acc[1]), pack2(acc[2], acc[3]),
                            pack2(acc[4], acc[5]), pack2(acc[6], acc[7]));
    uhat[(((size_t)bb * I_ + i) * OD_ + (size_t)t * 8) >> 3] = outv;
  }
}

// ---------- K2: iter-0 weighted sum. c is exactly uniform (1/64) -> plain sum over i ----------
// Block = (b, chunk of 32 i's). Deterministic partials, no atomics.
__global__ __launch_bounds__(256) void k_sum0(const uint4* __restrict__ uhat,
                                              float* __restrict__ part) {
  const int b = blockIdx.x >> 5, chunk = blockIdx.x & 31;
  const int t = threadIdx.x;
  float acc[8] = {0.f, 0.f, 0.f, 0.f, 0.f, 0.f, 0.f, 0.f};
  for (int ii = 0; ii < 32; ++ii) {
    const int i = chunk * 32 + ii;
    uint4 r = uhat[(((size_t)b * I_ + i) * OD_ + (size_t)t * 8) >> 3];
    float u[8]; unpack8(r, u);
    #pragma unroll
    for (int j = 0; j < 8; ++j) acc[j] += u[j];
  }
  float* o = part + ((size_t)b * 32 + chunk) * OD_ + (size_t)t * 8;
  ((float4*)o)[0] = make_float4(acc[0], acc[1], acc[2], acc[3]);
  ((float4*)o)[1] = make_float4(acc[4], acc[5], acc[6], acc[7]);
}

// ---------- squash: reduce 32 chunk-partials, scale, (+bias), squash over d, write v ----------
// One wave per (b,o) row; lane&31 = d. Both half-waves duplicate d (harmless).
__global__ __launch_bounds__(256) void k_squash(const float* __restrict__ part,
                                                const float* __restrict__ bias,
                                                float* __restrict__ vout,
                                                float scale, int addBias) {
  const int lane = threadIdx.x & 63;
  const int row = blockIdx.x * 4 + (threadIdx.x >> 6);  // 0..2047 ; b=row>>6, o=row&63
  const int b = row >> 6, o = row & 63;
  const int d = lane & 31;
  const float* p = part + (size_t)b * (32 * OD_) + (size_t)o * 32 + d;
  float s = 0.f;
  // half-waves split the 32 chunks, then combine across halves
  const int c0 = (lane >> 5) * 16;
  for (int c = c0; c < c0 + 16; ++c) s += p[(size_t)c * OD_];
  s += __shfl_xor(s, 32);
  s *= scale;
  if (addBias) s += bias[o * 32 + d];
  float dot = s * s;
  #pragma unroll
  for (int off = 1; off <= 16; off <<= 1) dot += __shfl_xor(dot, off);
  float sc = dot / (1.f + dot) / sqrtf(dot + 1e-8f);
  if (lane < 32) vout[(size_t)row * 32 + d] = s * sc;
}

// ---------- routing pass (iters 1 and 2) ----------
// Block = (b, chunk of 32 i's). Per i: agreement a[o]=u.v (quad shuffle-reduce),
// wave-0 softmax over the 64 output capsules, s_acc += c*u in registers.
__global__ __launch_bounds__(256) void k_route(const uint4* __restrict__ uhat,
                                               const float* __restrict__ vprev,
                                               float* __restrict__ bij,
                                               float* __restrict__ part,
                                               int secondIter) {
  const int b = blockIdx.x >> 5, chunk = blockIdx.x & 31;
  const int t = threadIdx.x;
  __shared__ float abuf[64];
  __shared__ float cbuf[64];
  float vreg[8];
  {
    const float4* vp = (const float4*)(vprev + (size_t)b * OD_ + (size_t)t * 8);
    float4 v0 = vp[0], v1 = vp[1];
    vreg[0] = v0.x; vreg[1] = v0.y; vreg[2] = v0.z; vreg[3] = v0.w;
    vreg[4] = v1.x; vreg[5] = v1.y; vreg[6] = v1.z; vreg[7] = v1.w;
  }
  float s_acc[8] = {0.f, 0.f, 0.f, 0.f, 0.f, 0.f, 0.f, 0.f};
  for (int ii = 0; ii < 32; ++ii) {
    const int i = chunk * 32 + ii;
    uint4 r = uhat[(((size_t)b * I_ + i) * OD_ + (size_t)t * 8) >> 3];
    float u[8]; unpack8(r, u);
    float p = 0.f;
    #pragma unroll
    for (int j = 0; j < 8; ++j) p = fmaf(u[j], vreg[j], p);
    // 4 threads per o (8 d's each): quad reduce
    p += __shfl_xor(p, 1);
    p += __shfl_xor(p, 2);
    if ((t & 3) == 0) abuf[t >> 2] = p;   // o = t>>2 in [0,64)
    __syncthreads();
    if (t < 64) {  // wave 0: softmax over o, update b_ij
      float a = abuf[t];
      const size_t bidx = ((size_t)b * I_ + i) * 64 + t;
      float bn;
      if (secondIter) bn = bij[bidx] + a;
      else            { bn = a; bij[bidx] = bn; }
      float m = bn;
      #pragma unroll
      for (int off = 1; off <= 32; off <<= 1) m = fmaxf(m, __shfl_xor(m, off));
      float e = __expf(bn - m);
      float sm = e;
      #pragma unroll
      for (int off = 1; off <= 32; off <<= 1) sm += __shfl_xor(sm, off);
      cbuf[t] = e / sm;
    }
    __syncthreads();
    const float c = cbuf[t >> 2];
    #pragma unroll
    for (int j = 0; j < 8; ++j) s_acc[j] = fmaf(c, u[j], s_acc[j]);
    // no 3rd barrier needed: next-iter abuf write is ordered after this iter's
    // abuf reads by the barrier above; cbuf reads finish before next-iter's
    // cbuf write (which is behind next iter's first barrier).
  }
  float* o = part + ((size_t)b * 32 + chunk) * OD_ + (size_t)t * 8;
  ((float4*)o)[0] = make_float4(s_acc[0], s_acc[1], s_acc[2], s_acc[3]);
  ((float4*)o)[1] = make_float4(s_acc[4], s_acc[5], s_acc[6], s_acc[7]);
}

extern "C" void kernel_launch(void* const* d_in, const int* in_sizes, int n_in,
                              void* d_out, int out_size, void* d_ws, size_t ws_size,
                              hipStream_t stream) {
  const float* x    = (const float*)d_in[0];  // [32,1024,16]
  const float* W    = (const float*)d_in[1];  // [1,1024,64,32,16]
  const float* bias = (const float*)d_in[2];  // [1,1,64,32]
  float* out = (float*)d_out;                 // [32,64,32]

  char* ws = (char*)d_ws;
  uint4* uhat = (uint4*)ws;                                   // 128 MB bf16 u_hat
  float* bij  = (float*)(ws + 134217728ull);                  // 8 MB  b_ij[b,i,o]
  float* part = (float*)(ws + 134217728ull + 8388608ull);     // 8 MB  s partials [b,chunk,od]
  float* vbuf = (float*)(ws + 134217728ull + 16777216ull);    // 256 KB v[b,od]

  k_einsum<<<dim3(I_), dim3(256), 0, stream>>>(x, W, uhat);
  // iter 0: uniform c = 1/64
  k_sum0  <<<dim3(1024), dim3(256), 0, stream>>>(uhat, part);
  k_squash<<<dim3(512),  dim3(256), 0, stream>>>(part, bias, vbuf, 1.f / 64.f, 0);
  // iter 1
  k_route <<<dim3(1024), dim3(256), 0, stream>>>(uhat, vbuf, bij, part, 0);
  k_squash<<<dim3(512),  dim3(256), 0, stream>>>(part, bias, vbuf, 1.f, 0);
  // iter 2 (last): + bias, output
  k_route <<<dim3(1024), dim3(256), 0, stream>>>(uhat, vbuf, bij, part, 1);
  k_squash<<<dim3(512),  dim3(256), 0, stream>>>(part, bias, out, 1.f, 1);
}

// Round 2
// 336.506 us; speedup vs baseline: 1.0285x; 1.0285x over previous
//
#include <hip/hip_runtime.h>
#include <hip/hip_bf16.h>
#include <stdint.h>

// Problem constants (FC_Caps): B=32, I=1024, O=64, D_out=32, D_in=16
#define B_  32
#define I_  1024
#define O_  64
#define D_  32
#define N_  16
#define OD_ 2048   // O_*D_

// ---------- bf16 helpers (bit-exact RNE pack, shift unpack) ----------
__device__ __forceinline__ uint32_t f2bf1(float f) {
  uint32_t u = __float_as_uint(f);
  return (u + 0x7fffu + ((u >> 16) & 1u)) >> 16;
}
__device__ __forceinline__ uint32_t pack2(float a, float b) {
  return f2bf1(a) | (f2bf1(b) << 16);
}
__device__ __forceinline__ void unpack8(uint4 r, float u[8]) {
  u[0] = __uint_as_float(r.x << 16);
  u[1] = __uint_as_float(r.x & 0xffff0000u);
  u[2] = __uint_as_float(r.y << 16);
  u[3] = __uint_as_float(r.y & 0xffff0000u);
  u[4] = __uint_as_float(r.z << 16);
  u[5] = __uint_as_float(r.z & 0xffff0000u);
  u[6] = __uint_as_float(r.w << 16);
  u[7] = __uint_as_float(r.w & 0xffff0000u);
}

// ---------- K1: u_hat[b][i][od] = sum_n W[i,od,n] * x[b,i,n]  (bf16 out) ----------
// Block = (i, od-half). Thread owns 4 od rows (64 VGPR W-tile), loops 32 batches.
// Grid 2048, ~5 waves/SIMD occupancy. Stores: uint2 (8B) fully coalesced.
__global__ __launch_bounds__(256) void k_einsum(const float* __restrict__ x,
                                                const float* __restrict__ W,
                                                uint2* __restrict__ uhat) {
  const int i = blockIdx.x >> 1;
  const int half = blockIdx.x & 1;
  const int t = threadIdx.x;
  const int od_base = half * 1024 + t * 4;
  __shared__ float xs[B_ * N_];
  for (int e = t; e < B_ * N_; e += 256) {
    int bb = e >> 4, n = e & 15;
    xs[e] = x[(size_t)bb * (I_ * N_) + (size_t)i * N_ + n];
  }
  // W[i, od, n] flat = i*32768 + od*16 + n ; thread's 4 rows contiguous (256 floats)
  float w[4][16];
  const float* Wi = W + (size_t)i * (OD_ * N_) + (size_t)od_base * N_;
  #pragma unroll
  for (int k = 0; k < 4; ++k) {
    #pragma unroll
    for (int q = 0; q < 4; ++q) {
      float4 f = ((const float4*)(Wi + k * 16))[q];
      w[k][q * 4 + 0] = f.x; w[k][q * 4 + 1] = f.y;
      w[k][q * 4 + 2] = f.z; w[k][q * 4 + 3] = f.w;
    }
  }
  __syncthreads();
  for (int bb = 0; bb < B_; ++bb) {
    float xv[16];
    #pragma unroll
    for (int q = 0; q < 4; ++q) {
      float4 f = ((const float4*)(xs + bb * 16))[q];   // LDS broadcast
      xv[q * 4 + 0] = f.x; xv[q * 4 + 1] = f.y;
      xv[q * 4 + 2] = f.z; xv[q * 4 + 3] = f.w;
    }
    float acc[4];
    #pragma unroll
    for (int k = 0; k < 4; ++k) {
      float a = 0.f;
      #pragma unroll
      for (int n = 0; n < 16; ++n) a = fmaf(w[k][n], xv[n], a);
      acc[k] = a;
    }
    uhat[(((size_t)bb * I_ + i) * OD_ + od_base) >> 2] =
        make_uint2(pack2(acc[0], acc[1]), pack2(acc[2], acc[3]));
  }
}

// ---------- K2: iter-0 weighted sum. c exactly uniform (1/64) -> plain sum over i ----------
__global__ __launch_bounds__(256) void k_sum0(const uint4* __restrict__ uhat,
                                              float* __restrict__ part) {
  const int b = blockIdx.x >> 5, chunk = blockIdx.x & 31;
  const int t = threadIdx.x;
  float acc[8] = {0.f, 0.f, 0.f, 0.f, 0.f, 0.f, 0.f, 0.f};
  for (int ii = 0; ii < 32; ++ii) {
    const int i = chunk * 32 + ii;
    uint4 r = uhat[(((size_t)b * I_ + i) * OD_ + (size_t)t * 8) >> 3];
    float u[8]; unpack8(r, u);
    #pragma unroll
    for (int j = 0; j < 8; ++j) acc[j] += u[j];
  }
  float* o = part + ((size_t)b * 32 + chunk) * OD_ + (size_t)t * 8;
  ((float4*)o)[0] = make_float4(acc[0], acc[1], acc[2], acc[3]);
  ((float4*)o)[1] = make_float4(acc[4], acc[5], acc[6], acc[7]);
}

// ---------- squash: reduce 32 chunk-partials, scale, (+bias), squash over d ----------
__global__ __launch_bounds__(256) void k_squash(const float* __restrict__ part,
                                                const float* __restrict__ bias,
                                                float* __restrict__ vout,
                                                float scale, int addBias) {
  const int lane = threadIdx.x & 63;
  const int row = blockIdx.x * 4 + (threadIdx.x >> 6);  // b=row>>6, o=row&63
  const int b = row >> 6, o = row & 63;
  const int d = lane & 31;
  const float* p = part + (size_t)b * (32 * OD_) + (size_t)o * 32 + d;
  float s = 0.f;
  const int c0 = (lane >> 5) * 16;
  for (int c = c0; c < c0 + 16; ++c) s += p[(size_t)c * OD_];
  s += __shfl_xor(s, 32);
  s *= scale;
  if (addBias) s += bias[o * 32 + d];
  float dot = s * s;
  #pragma unroll
  for (int off = 1; off <= 16; off <<= 1) dot += __shfl_xor(dot, off);
  float sc = dot / (1.f + dot) / sqrtf(dot + 1e-8f);
  if (lane < 32) vout[(size_t)row * 32 + d] = s * sc;
}

// ---------- routing pass (iters 1 and 2), 3-phase, 2 barriers total ----------
// Block = (b, chunk of 32 i). A: agreements -> LDS. B: softmax (all threads).
// C: re-read u_hat (LLC-hot), accumulate c*u.
#define PAD_ 65
__global__ __launch_bounds__(256) void k_route(const uint4* __restrict__ uhat,
                                               const float* __restrict__ vprev,
                                               float* __restrict__ bij,
                                               float* __restrict__ part,
                                               int secondIter) {
  const int b = blockIdx.x >> 5, chunk = blockIdx.x & 31;
  const int t = threadIdx.x;
  __shared__ float abuf[32 * PAD_];
  __shared__ float cbuf[32 * PAD_];
  float vreg[8];
  {
    const float4* vp = (const float4*)(vprev + (size_t)b * OD_ + (size_t)t * 8);
    float4 v0 = vp[0], v1 = vp[1];
    vreg[0] = v0.x; vreg[1] = v0.y; vreg[2] = v0.z; vreg[3] = v0.w;
    vreg[4] = v1.x; vreg[5] = v1.y; vreg[6] = v1.z; vreg[7] = v1.w;
  }
  const size_t ubase = (((size_t)b * I_ + (size_t)chunk * 32) * OD_ + (size_t)t * 8) >> 3;
  // --- Phase A: agreements a[ii][o] for all 32 i's ---
  for (int ii = 0; ii < 32; ++ii) {
    uint4 r = uhat[ubase + (size_t)ii * (OD_ / 8)];
    float u[8]; unpack8(r, u);
    float p = 0.f;
    #pragma unroll
    for (int j = 0; j < 8; ++j) p = fmaf(u[j], vreg[j], p);
    p += __shfl_xor(p, 1);
    p += __shfl_xor(p, 2);
    if ((t & 3) == 0) abuf[ii * PAD_ + (t >> 2)] = p;
  }
  __syncthreads();
  // --- Phase B: softmax over o per i-row. 8 threads/row, 8 o's each ---
  {
    const int ii = t >> 3;
    const int ob = (t & 7) * 8;
    const int i = chunk * 32 + ii;
    float bn[8];
    const size_t bidx = ((size_t)b * I_ + i) * 64 + ob;
    if (secondIter) {
      float4 b0 = ((const float4*)(bij + bidx))[0];
      float4 b1 = ((const float4*)(bij + bidx))[1];
      bn[0] = b0.x + abuf[ii * PAD_ + ob + 0];
      bn[1] = b0.y + abuf[ii * PAD_ + ob + 1];
      bn[2] = b0.z + abuf[ii * PAD_ + ob + 2];
      bn[3] = b0.w + abuf[ii * PAD_ + ob + 3];
      bn[4] = b1.x + abuf[ii * PAD_ + ob + 4];
      bn[5] = b1.y + abuf[ii * PAD_ + ob + 5];
      bn[6] = b1.z + abuf[ii * PAD_ + ob + 6];
      bn[7] = b1.w + abuf[ii * PAD_ + ob + 7];
    } else {
      #pragma unroll
      for (int j = 0; j < 8; ++j) bn[j] = abuf[ii * PAD_ + ob + j];
      ((float4*)(bij + bidx))[0] = make_float4(bn[0], bn[1], bn[2], bn[3]);
      ((float4*)(bij + bidx))[1] = make_float4(bn[4], bn[5], bn[6], bn[7]);
    }
    float m = bn[0];
    #pragma unroll
    for (int j = 1; j < 8; ++j) m = fmaxf(m, bn[j]);
    m = fmaxf(m, __shfl_xor(m, 1));
    m = fmaxf(m, __shfl_xor(m, 2));
    m = fmaxf(m, __shfl_xor(m, 4));
    float e[8], sm = 0.f;
    #pragma unroll
    for (int j = 0; j < 8; ++j) { e[j] = __expf(bn[j] - m); sm += e[j]; }
    sm += __shfl_xor(sm, 1);
    sm += __shfl_xor(sm, 2);
    sm += __shfl_xor(sm, 4);
    float inv = 1.f / sm;
    #pragma unroll
    for (int j = 0; j < 8; ++j) cbuf[ii * PAD_ + ob + j] = e[j] * inv;
  }
  __syncthreads();
  // --- Phase C: s_acc += c * u ---
  float s_acc[8] = {0.f, 0.f, 0.f, 0.f, 0.f, 0.f, 0.f, 0.f};
  const int oq = t >> 2;  // this thread's o (4 lanes per o)
  for (int ii = 0; ii < 32; ++ii) {
    uint4 r = uhat[ubase + (size_t)ii * (OD_ / 8)];
    float u[8]; unpack8(r, u);
    const float c = cbuf[ii * PAD_ + oq];
    #pragma unroll
    for (int j = 0; j < 8; ++j) s_acc[j] = fmaf(c, u[j], s_acc[j]);
  }
  float* o = part + ((size_t)b * 32 + chunk) * OD_ + (size_t)t * 8;
  ((float4*)o)[0] = make_float4(s_acc[0], s_acc[1], s_acc[2], s_acc[3]);
  ((float4*)o)[1] = make_float4(s_acc[4], s_acc[5], s_acc[6], s_acc[7]);
}

extern "C" void kernel_launch(void* const* d_in, const int* in_sizes, int n_in,
                              void* d_out, int out_size, void* d_ws, size_t ws_size,
                              hipStream_t stream) {
  const float* x    = (const float*)d_in[0];  // [32,1024,16]
  const float* W    = (const float*)d_in[1];  // [1,1024,64,32,16]
  const float* bias = (const float*)d_in[2];  // [1,1,64,32]
  float* out = (float*)d_out;                 // [32,64,32]

  char* ws = (char*)d_ws;
  uint2* uhat2 = (uint2*)ws;                                  // 128 MB bf16 u_hat
  uint4* uhat4 = (uint4*)ws;
  float* bij  = (float*)(ws + 134217728ull);                  // 8 MB  b_ij[b,i,o]
  float* part = (float*)(ws + 134217728ull + 8388608ull);     // 8 MB  s partials
  float* vbuf = (float*)(ws + 134217728ull + 16777216ull);    // 256 KB v[b,od]

  k_einsum<<<dim3(I_ * 2), dim3(256), 0, stream>>>(x, W, uhat2);
  // iter 0: uniform c = 1/64
  k_sum0  <<<dim3(1024), dim3(256), 0, stream>>>(uhat4, part);
  k_squash<<<dim3(512),  dim3(256), 0, stream>>>(part, bias, vbuf, 1.f / 64.f, 0);
  // iter 1
  k_route <<<dim3(1024), dim3(256), 0, stream>>>(uhat4, vbuf, bij, part, 0);
  k_squash<<<dim3(512),  dim3(256), 0, stream>>>(part, bias, vbuf, 1.f, 0);
  // iter 2 (last): + bias, output
  k_route <<<dim3(1024), dim3(256), 0, stream>>>(uhat4, vbuf, bij, part, 1);
  k_squash<<<dim3(512),  dim3(256), 0, stream>>>(part, bias, out, 1.f, 1);
}